// Round 4
// baseline (23638.690 us; speedup 1.0000x reference)
//
#include <hip/hip_runtime.h>
#include <math.h>

// IDE state-space Kalman filter, MI355X (gfx950). Round 4:
// - register-resident 16x16 chol-diag inverse (shfl, no LDS chain)
// - float4 reads in chol trailing + trinv
// - symmetric-output lower-tile-only matmuls for P'=A P A^T and Pn=r2 M^T Y,
//   with block-transposed float4 mirror passes
// - Wm(=Sm) staging fused into the P' mirror; one-pass A build w/ shfl norm

#define SQ 64
#define DQ 128
#define TQ 128
#define BQ 16
#define LDP 132           // padded LDS row stride (floats); rows 16B-aligned
#define NTH 1024
#define LOG2PI 1.8378770664093454f

#define SMEM_FLOATS 36648

__device__ __forceinline__ float block_reduce_sum(float v, float* red) {
  #pragma unroll
  for (int off = 32; off > 0; off >>= 1) v += __shfl_down(v, off);
  const int tid = threadIdx.x;
  if ((tid & 63) == 0) red[tid >> 6] = v;
  __syncthreads();
  v = 0.0f;
  #pragma unroll
  for (int w = 0; w < NTH / 64; w++) v += red[w];
  __syncthreads();
  return v;
}

__device__ __forceinline__ void tri_index(int tid, int& br, int& bc) {
  float f = (sqrtf(8.0f * (float)tid + 1.0f) - 1.0f) * 0.5f;
  br = (int)f;
  if ((br + 1) * (br + 2) / 2 <= tid) br++;
  else if (br * (br + 1) / 2 > tid) br--;
  bc = tid - br * (br + 1) / 2;
}

// Measurement update: nll += term, m += P*Sinv*v, P = r2 * Sinv * P.
// If stageW: copies Pm->Wm and adds r2 to diag first (t=0 path); otherwise
// Wm must already hold P + r2*I.
__device__ void kf_update(const float* __restrict__ zt, float r2,
                          float* Pm, float* Wm, float* gtmp,
                          float* mv, float* vv, float* yv, float* xv,
                          float* mdiag, float* red, float& nll, bool stageW) {
  const int tid = threadIdx.x;
  const int lane = tid & 63;
  const int z  = tid >> 9;          // matmul half (k-parity)
  const int t9 = tid & 511;
  const int cg = t9 & 15, rg = t9 >> 4;
  const int r0 = rg * 4, cL = cg * 4, cR = 64 + cg * 4;

  if (tid < DQ) vv[tid] = zt[tid] - mv[tid];
  if (stageW) {
    for (int e = tid; e < (DQ * LDP) / 4; e += NTH)
      ((float4*)Wm)[e] = ((const float4*)Pm)[e];
    __syncthreads();
    if (tid < DQ) Wm[tid * LDP + tid] += r2;
    __syncthreads();
  }

  // ---- blocked Cholesky (lower), NB=16, with register diag inverse ----
  #pragma unroll 1
  for (int kb = 0; kb < 8; kb++) {
    const int b0 = kb * 16;
    if (tid < 64) {
      float* Wd = Wm + b0 * LDP + b0;
      float a[16];
      if (lane < 16) {
        const float4* rp = (const float4*)(Wd + lane * LDP);
        float4 q0 = rp[0], q1 = rp[1], q2v = rp[2], q3 = rp[3];
        a[0]=q0.x; a[1]=q0.y; a[2]=q0.z; a[3]=q0.w;
        a[4]=q1.x; a[5]=q1.y; a[6]=q1.z; a[7]=q1.w;
        a[8]=q2v.x; a[9]=q2v.y; a[10]=q2v.z; a[11]=q2v.w;
        a[12]=q3.x; a[13]=q3.y; a[14]=q3.z; a[15]=q3.w;
      } else {
        #pragma unroll
        for (int i = 0; i < 16; i++) a[i] = 1.0f;
      }
      float dinv_l = 1.0f;
      #pragma unroll
      for (int j = 0; j < 16; j++) {
        float dj  = __shfl(a[j], j);
        float ljj = sqrtf(dj);
        float inv = 1.0f / ljj;
        float lij = a[j] * inv;
        a[j] = (lane == j) ? ljj : lij;
        if (lane == j) dinv_l = inv;
        #pragma unroll
        for (int l = j + 1; l < 16; l++) {
          float llj = __shfl(a[j], l);
          a[l] = fmaf(-lij, llj, a[l]);
        }
      }
      if (lane < 16) {
        float4* rp = (float4*)(Wd + lane * LDP);
        rp[0] = make_float4(a[0], a[1], a[2], a[3]);
        rp[1] = make_float4(a[4], a[5], a[6], a[7]);
        rp[2] = make_float4(a[8], a[9], a[10], a[11]);
        rp[3] = make_float4(a[12], a[13], a[14], a[15]);
      }
      // register inverse of the 16x16 lower triangle: lane c holds col c.
      float x[16];
      #pragma unroll
      for (int i = 0; i < 16; i++) {
        float s = (i == lane) ? 1.0f : 0.0f;
        #pragma unroll
        for (int k = 0; k < 16; k++) {
          if (k < i) {
            float Lik = __shfl(a[k], i);
            s = fmaf(-Lik, x[k], s);
          }
        }
        float di = __shfl(dinv_l, i);
        x[i] = (i < lane) ? 0.0f : s * di;
      }
      if (lane < 16) {
        mdiag[b0 + lane] = x[lane];
        #pragma unroll
        for (int i = 0; i < 16; i++)
          if (i > lane) Wm[(b0 + lane) * LDP + (b0 + i)] = x[i];
      }
    }
    __syncthreads();
    if (kb == 7) break;
    const int base = b0 + 16;
    const int nbelow = DQ - base;
    // (b) panel: L_panel = W_panel * Ldiag^{-T}
    {
      const int rr = tid >> 4, j = tid & 15;
      const int rA = base + rr, rB = rA + 64;
      const float md = mdiag[b0 + j];
      float outA = 0.0f, outB = 0.0f;
      const bool vA = rr < nbelow;
      const bool vB = rr + 64 < nbelow;
      if (vA) {
        const float* wr = Wm + rA * LDP + b0;
        float s = 0.0f;
        for (int l = 0; l < j; l++)
          s = fmaf(wr[l], Wm[(b0 + l) * LDP + (b0 + j)], s);
        outA = fmaf(wr[j], md, s);
      }
      if (vB) {
        const float* wr = Wm + rB * LDP + b0;
        float s = 0.0f;
        for (int l = 0; l < j; l++)
          s = fmaf(wr[l], Wm[(b0 + l) * LDP + (b0 + j)], s);
        outB = fmaf(wr[j], md, s);
      }
      __syncthreads();
      if (vA) Wm[rA * LDP + b0 + j] = outA;
      if (vB) Wm[rB * LDP + b0 + j] = outB;
    }
    __syncthreads();
    // (c) trailing update by 16x16 blocks (lower only), float4 dots
    {
      const int z4 = tid >> 8;
      const int t8 = tid & 255;
      const int mrow = t8 >> 4, mcol = t8 & 15;
      const int mb = 7 - kb;
      int cnt = 0;
      for (int bi = 0; bi < mb; bi++) {
        for (int bj = 0; bj <= bi; bj++) {
          if ((cnt & 3) == z4 && (bi > bj || mrow >= mcol)) {
            const int i = base + bi * 16 + mrow;
            const int j = base + bj * 16 + mcol;
            const float* pi = Wm + i * LDP + b0;
            const float* pj = Wm + j * LDP + b0;
            float s = 0.0f;
            #pragma unroll
            for (int c4 = 0; c4 < 4; c4++) {
              float4 xa = *(const float4*)&pi[c4 * 4];
              float4 yb = *(const float4*)&pj[c4 * 4];
              s = fmaf(xa.x, yb.x, s);
              s = fmaf(xa.y, yb.y, s);
              s = fmaf(xa.z, yb.z, s);
              s = fmaf(xa.w, yb.w, s);
            }
            Wm[i * LDP + j] -= s;
          }
          cnt++;
        }
      }
    }
    __syncthreads();
  }

  float ldv = (tid < DQ) ? __logf(mdiag[tid]) : 0.0f;
  float logdet = -2.0f * block_reduce_sum(ldv, red);

  // ---- off-diagonal blocks of M = L^-1 (transposed-upper storage) ----
  #pragma unroll 1
  for (int d = 1; d < 8; d++) {
    const int z4 = tid >> 8;
    const int t8 = tid & 255;
    const int i16 = t8 >> 4, j16 = t8 & 15;
    for (int nb = z4; nb + d < 8; nb += 4) {
      const int J = nb, I = nb + d;
      const float* Lrow = Wm + (I * 16 + i16) * LDP + J * 16;
      const float* Mrow = Wm + (J * 16 + j16) * LDP + J * 16;
      const float md = mdiag[J * 16 + j16];
      float g = 0.0f;
      #pragma unroll
      for (int c4 = 0; c4 < 4; c4++) {
        float4 lv = *(const float4*)&Lrow[c4 * 4];
        float4 mq = *(const float4*)&Mrow[c4 * 4];
        float w0 = (c4*4+0 > j16) ? mq.x : ((c4*4+0 == j16) ? md : 0.0f);
        float w1 = (c4*4+1 > j16) ? mq.y : ((c4*4+1 == j16) ? md : 0.0f);
        float w2 = (c4*4+2 > j16) ? mq.z : ((c4*4+2 == j16) ? md : 0.0f);
        float w3 = (c4*4+3 > j16) ? mq.w : ((c4*4+3 == j16) ? md : 0.0f);
        g = fmaf(lv.x, w0, g); g = fmaf(lv.y, w1, g);
        g = fmaf(lv.z, w2, g); g = fmaf(lv.w, w3, g);
      }
      for (int K = J + 1; K < I; K++) {
        const float* LK = Lrow + (K - J) * 16;
        const float* MK = Wm + (J * 16 + j16) * LDP + K * 16;
        #pragma unroll
        for (int c4 = 0; c4 < 4; c4++) {
          float4 lv = *(const float4*)&LK[c4 * 4];
          float4 mq = *(const float4*)&MK[c4 * 4];
          g = fmaf(lv.x, mq.x, g); g = fmaf(lv.y, mq.y, g);
          g = fmaf(lv.z, mq.z, g); g = fmaf(lv.w, mq.w, g);
        }
      }
      gtmp[nb * 256 + t8] = g;
    }
    __syncthreads();
    for (int nb = z4; nb + d < 8; nb += 4) {
      const int J = nb, I = nb + d;
      const float* gb = gtmp + nb * 256;
      float s = mdiag[I * 16 + i16] * gb[i16 * 16 + j16];
      for (int k = 0; k < i16; k++)
        s = fmaf(Wm[(I * 16 + k) * LDP + I * 16 + i16], gb[k * 16 + j16], s);
      Wm[(J * 16 + j16) * LDP + (I * 16 + i16)] = -s;
    }
    __syncthreads();
  }

  // ---- y = M v (4-way k-split) ----
  if (tid < 512) {
    const int i = tid & 127, q = tid >> 7;
    const int k0 = q * 32;
    const int k1 = min(k0 + 32, i);
    float s = 0.0f;
    for (int k = k0; k < k1; k++) s = fmaf(Wm[k * LDP + i], vv[k], s);
    if (q == (i >> 5)) s = fmaf(mdiag[i], vv[i], s);
    gtmp[i * 4 + q] = s;
  }
  __syncthreads();
  if (tid < DQ)
    yv[tid] = gtmp[4 * tid] + gtmp[4 * tid + 1] + gtmp[4 * tid + 2] + gtmp[4 * tid + 3];
  __syncthreads();
  float qv = (tid < DQ) ? yv[tid] * yv[tid] : 0.0f;
  float quad = block_reduce_sum(qv, red);
  // ---- x = M^T y (4-way k-split) ----
  if (tid < 512) {
    const int i = tid & 127, q = tid >> 7;
    const int k0 = max(q * 32, i + 1);
    const int k1 = q * 32 + 32;
    float s = 0.0f;
    for (int k = k0; k < k1; k++) s = fmaf(Wm[i * LDP + k], yv[k], s);
    if (q == (i >> 5)) s = fmaf(mdiag[i], yv[i], s);
    gtmp[i * 4 + q] = s;
  }
  __syncthreads();
  if (tid < DQ)
    xv[tid] = gtmp[4 * tid] + gtmp[4 * tid + 1] + gtmp[4 * tid + 2] + gtmp[4 * tid + 3];
  __syncthreads();
  // ---- m += P x (8-way k-split) ----
  {
    const int r = tid >> 3, q8 = tid & 7;
    const float* prow = Pm + r * LDP + q8 * 16;
    const float* xq = xv + q8 * 16;
    float s = 0.0f;
    #pragma unroll
    for (int k = 0; k < 16; k++) s = fmaf(prow[k], xq[k], s);
    gtmp[r * 8 + q8] = s;
  }
  __syncthreads();
  if (tid < DQ) {
    float s = mv[tid];
    #pragma unroll
    for (int u = 0; u < 8; u++) s += gtmp[8 * tid + u];
    mv[tid] = s;
  }
  nll += 0.5f * (quad + logdet + (float)DQ * LOG2PI);

  // ---- Y = M * P (triangular: k <= row), z-split, full output ----
  float acc[4][8];
  #pragma unroll
  for (int i = 0; i < 4; i++)
    #pragma unroll
    for (int j = 0; j < 8; j++) acc[i][j] = 0.0f;
  if (z == 0) {
    #pragma unroll
    for (int kk = 0; kk < 4; kk++) {
      float4 pL = *(const float4*)&Pm[(r0 + kk) * LDP + cL];
      float4 pR = *(const float4*)&Pm[(r0 + kk) * LDP + cR];
      float pp[8] = {pL.x, pL.y, pL.z, pL.w, pR.x, pR.y, pR.z, pR.w};
      #pragma unroll
      for (int i = 0; i < 4; i++) {
        float coef = (kk < i) ? Wm[(r0 + kk) * LDP + r0 + i]
                   : ((kk == i) ? mdiag[r0 + i] : 0.0f);
        #pragma unroll
        for (int j = 0; j < 8; j++) acc[i][j] = fmaf(coef, pp[j], acc[i][j]);
      }
    }
  }
  for (int c = z; c < rg; c += 2) {
    const int k = c * 4;
    float cv[4][4];
    #pragma unroll
    for (int kk = 0; kk < 4; kk++) {
      float4 c4 = *(const float4*)&Wm[(k + kk) * LDP + r0];
      cv[kk][0] = c4.x; cv[kk][1] = c4.y; cv[kk][2] = c4.z; cv[kk][3] = c4.w;
    }
    #pragma unroll
    for (int kk = 0; kk < 4; kk++) {
      float4 pL = *(const float4*)&Pm[(k + kk) * LDP + cL];
      float4 pR = *(const float4*)&Pm[(k + kk) * LDP + cR];
      float pp[8] = {pL.x, pL.y, pL.z, pL.w, pR.x, pR.y, pR.z, pR.w};
      #pragma unroll
      for (int i = 0; i < 4; i++)
        #pragma unroll
        for (int j = 0; j < 8; j++) acc[i][j] = fmaf(cv[kk][i], pp[j], acc[i][j]);
    }
  }
  __syncthreads();
  if (z == 0) {
    #pragma unroll
    for (int i = 0; i < 4; i++) {
      *(float4*)&Pm[(r0 + i) * LDP + cL] = make_float4(acc[i][0], acc[i][1], acc[i][2], acc[i][3]);
      *(float4*)&Pm[(r0 + i) * LDP + cR] = make_float4(acc[i][4], acc[i][5], acc[i][6], acc[i][7]);
    }
  }
  __syncthreads();
  if (z == 1) {
    #pragma unroll
    for (int i = 0; i < 4; i++) {
      float4 vL = *(float4*)&Pm[(r0 + i) * LDP + cL];
      float4 vR = *(float4*)&Pm[(r0 + i) * LDP + cR];
      vL.x += acc[i][0]; vL.y += acc[i][1]; vL.z += acc[i][2]; vL.w += acc[i][3];
      vR.x += acc[i][4]; vR.y += acc[i][5]; vR.z += acc[i][6]; vR.w += acc[i][7];
      *(float4*)&Pm[(r0 + i) * LDP + cL] = vL;
      *(float4*)&Pm[(r0 + i) * LDP + cR] = vR;
    }
  }
  __syncthreads();

  // ---- P = r2 * (M^T * Y): symmetric output, lower tiles only ----
  const bool doL = (rg >= cg), doR = (rg >= cg + 16);
  #pragma unroll
  for (int i = 0; i < 4; i++)
    #pragma unroll
    for (int j = 0; j < 8; j++) acc[i][j] = 0.0f;
  if (doL) {
    if (z == 0) {
      #pragma unroll
      for (int kk = 0; kk < 4; kk++) {
        float coef[4];
        #pragma unroll
        for (int i = 0; i < 4; i++)
          coef[i] = (kk > i) ? Wm[(r0 + i) * LDP + r0 + kk]
                   : ((kk == i) ? mdiag[r0 + i] : 0.0f);
        float4 pL = *(const float4*)&Pm[(r0 + kk) * LDP + cL];
        float pl[4] = {pL.x, pL.y, pL.z, pL.w};
        #pragma unroll
        for (int i = 0; i < 4; i++)
          #pragma unroll
          for (int j = 0; j < 4; j++) acc[i][j] = fmaf(coef[i], pl[j], acc[i][j]);
        if (doR) {
          float4 pR = *(const float4*)&Pm[(r0 + kk) * LDP + cR];
          float pr[4] = {pR.x, pR.y, pR.z, pR.w};
          #pragma unroll
          for (int i = 0; i < 4; i++)
            #pragma unroll
            for (int j = 0; j < 4; j++) acc[i][4 + j] = fmaf(coef[i], pr[j], acc[i][4 + j]);
        }
      }
    }
    const int cstart = rg + 1;
    for (int c = cstart + ((cstart ^ z) & 1); c < 32; c += 2) {
      const int k = c * 4;
      float av[4][4];
      #pragma unroll
      for (int i = 0; i < 4; i++) {
        float4 a4 = *(const float4*)&Wm[(r0 + i) * LDP + k];
        av[i][0] = a4.x; av[i][1] = a4.y; av[i][2] = a4.z; av[i][3] = a4.w;
      }
      #pragma unroll
      for (int kk = 0; kk < 4; kk++) {
        float4 pL = *(const float4*)&Pm[(k + kk) * LDP + cL];
        float pl[4] = {pL.x, pL.y, pL.z, pL.w};
        #pragma unroll
        for (int i = 0; i < 4; i++)
          #pragma unroll
          for (int j = 0; j < 4; j++) acc[i][j] = fmaf(av[i][kk], pl[j], acc[i][j]);
      }
      if (doR) {
        #pragma unroll
        for (int kk = 0; kk < 4; kk++) {
          float4 pR = *(const float4*)&Pm[(k + kk) * LDP + cR];
          float pr[4] = {pR.x, pR.y, pR.z, pR.w};
          #pragma unroll
          for (int i = 0; i < 4; i++)
            #pragma unroll
            for (int j = 0; j < 4; j++) acc[i][4 + j] = fmaf(av[i][kk], pr[j], acc[i][4 + j]);
        }
      }
    }
  }
  __syncthreads();
  if (z == 0 && doL) {
    #pragma unroll
    for (int i = 0; i < 4; i++)
      *(float4*)&Pm[(r0 + i) * LDP + cL] =
          make_float4(r2 * acc[i][0], r2 * acc[i][1], r2 * acc[i][2], r2 * acc[i][3]);
    if (doR) {
      #pragma unroll
      for (int i = 0; i < 4; i++)
        *(float4*)&Pm[(r0 + i) * LDP + cR] =
            make_float4(r2 * acc[i][4], r2 * acc[i][5], r2 * acc[i][6], r2 * acc[i][7]);
    }
  }
  __syncthreads();
  if (z == 1 && doL) {
    #pragma unroll
    for (int i = 0; i < 4; i++) {
      float4 vL = *(float4*)&Pm[(r0 + i) * LDP + cL];
      vL.x += r2 * acc[i][0]; vL.y += r2 * acc[i][1];
      vL.z += r2 * acc[i][2]; vL.w += r2 * acc[i][3];
      *(float4*)&Pm[(r0 + i) * LDP + cL] = vL;
    }
    if (doR) {
      #pragma unroll
      for (int i = 0; i < 4; i++) {
        float4 vR = *(float4*)&Pm[(r0 + i) * LDP + cR];
        vR.x += r2 * acc[i][4]; vR.y += r2 * acc[i][5];
        vR.z += r2 * acc[i][6]; vR.w += r2 * acc[i][7];
        *(float4*)&Pm[(r0 + i) * LDP + cR] = vR;
      }
    }
  }
  __syncthreads();
  // ---- mirror lower -> upper (4x4 block transpose) ----
  if (tid < 528) {
    int br, bc; tri_index(tid, br, bc);
    if (br > bc) {
      const int R = 4 * br, C = 4 * bc;
      float4 v0 = *(const float4*)&Pm[(R + 0) * LDP + C];
      float4 v1 = *(const float4*)&Pm[(R + 1) * LDP + C];
      float4 v2 = *(const float4*)&Pm[(R + 2) * LDP + C];
      float4 v3 = *(const float4*)&Pm[(R + 3) * LDP + C];
      *(float4*)&Pm[(C + 0) * LDP + R] = make_float4(v0.x, v1.x, v2.x, v3.x);
      *(float4*)&Pm[(C + 1) * LDP + R] = make_float4(v0.y, v1.y, v2.y, v3.y);
      *(float4*)&Pm[(C + 2) * LDP + R] = make_float4(v0.z, v1.z, v2.z, v3.z);
      *(float4*)&Pm[(C + 3) * LDP + R] = make_float4(v0.w, v1.w, v2.w, v3.w);
    }
  }
  __syncthreads();
}

extern "C" __global__ __launch_bounds__(NTH, 4)
void ide_kf_kernel(const float* __restrict__ z_seq,
                   const float* __restrict__ site_lon,
                   const float* __restrict__ site_lat,
                   const float* __restrict__ mu_seq,
                   const float* __restrict__ sigma_seq,
                   const float* __restrict__ log_q,
                   const float* __restrict__ log_r,
                   const float* __restrict__ log_p0,
                   const float* __restrict__ log_damp,
                   const float* __restrict__ init_mean,
                   const float* __restrict__ coupling_raw,
                   float* __restrict__ ws) {
  extern __shared__ float smem[];
  float* Pm     = smem;                  // 128*132
  float* Wm     = Pm + DQ * LDP;         // 128*132
  float* gtmp   = Wm + DQ * LDP;         // 2048
  float* coords = gtmp + 2048;           // 128
  float* mv     = coords + 128;          // 128
  float* vv     = mv + DQ;               // 128
  float* yv     = vv + DQ;               // 128
  float* xv     = yv + DQ;               // 128
  float* mdiag  = xv + DQ;               // 128
  float* tsb    = mdiag + DQ;            // 24
  float* red    = tsb + 24;              // 16

  const int tid = threadIdx.x;
  const int b = blockIdx.x;
  float* nll_out = ws;

  const float r2 = __expf(2.0f * log_r[0]);
  const float q2 = __expf(2.0f * log_q[0]);
  const float p0sq = __expf(2.0f * log_p0[0]);
  const float damping = __expf(log_damp[0]);
  const float cpl00 = 1.0f + 0.25f * tanhf(coupling_raw[0]);
  const float cpl01 = 0.25f * tanhf(coupling_raw[1]);
  const float cpl10 = 0.25f * tanhf(coupling_raw[2]);
  const float cpl11 = 1.0f + 0.25f * tanhf(coupling_raw[3]);

  const int z  = tid >> 9;
  const int t9 = tid & 511;
  const int cg = t9 & 15, rg = t9 >> 4;
  const int r0 = rg * 4, cL = cg * 4, cR = 64 + cg * 4;
  const bool doL = (rg >= cg), doR = (rg >= cg + 16);

  // ---- lon/lat projection ----
  float myLon = (tid < SQ) ? site_lon[tid] : 0.0f;
  float myLat = (tid < SQ) ? site_lat[tid] : 0.0f;
  float lat0 = block_reduce_sum(myLat, red) * (1.0f / 64.0f);
  float lon0 = block_reduce_sum(myLon, red) * (1.0f / 64.0f);
  if (tid < SQ) {
    const float km = 111.32f;
    float cs = cosf(lat0 * 0.017453292519943295f);
    coords[2 * tid]     = (myLon - lon0) * (km * cs);
    coords[2 * tid + 1] = (myLat - lat0) * km;
  }
  __syncthreads();
  float dsum = 0.0f, dcnt = 0.0f;
  for (int idx = tid; idx < SQ * SQ; idx += NTH) {
    int i = idx >> 6, j = idx & 63;
    float dx = coords[2 * i] - coords[2 * j];
    float dy = coords[2 * i + 1] - coords[2 * j + 1];
    float d = sqrtf(dx * dx + dy * dy + 1e-12f);
    dsum += d;
    if (d > 1e-6f) dcnt += 1.0f;
  }
  dsum = block_reduce_sum(dsum, red);
  dcnt = block_reduce_sum(dcnt, red);
  float scale = dsum / fmaxf(dcnt, 1.0f);
  float sdiv = 1.0f / fmaxf(scale, 1e-6f);
  if (tid < SQ) { coords[2 * tid] *= sdiv; coords[2 * tid + 1] *= sdiv; }

  // ---- init m, P; first measurement update (t=0) ----
  for (int e = tid; e < (DQ * LDP) / 4; e += NTH)
    ((float4*)Pm)[e] = make_float4(0.0f, 0.0f, 0.0f, 0.0f);
  __syncthreads();
  if (tid < DQ) { Pm[tid * LDP + tid] = p0sq; mv[tid] = init_mean[tid]; }
  __syncthreads();

  float nll = 0.0f;
  kf_update(z_seq + ((size_t)b * TQ) * DQ, r2, Pm, Wm, gtmp, mv, vv, yv, xv,
            mdiag, red, nll, true);

  // ---- time scan ----
  #pragma unroll 1
  for (int t = 1; t < TQ; t++) {
    const float* mu_t = mu_seq + ((size_t)b * (TQ - 1) + (t - 1)) * 4;
    const float* sg_t = sigma_seq + ((size_t)b * (TQ - 1) + (t - 1)) * 16;
    const float* zt = z_seq + ((size_t)b * TQ + t) * DQ;

    // per-(t,s) Gaussian parameters
    if (tid < 4) {
      const int tt = tid >> 1, ss = tid & 1;
      float m0v = mu_t[0], m1v = mu_t[1], m2v = mu_t[2], m3v = mu_t[3];
      float dmx, dmy, c00, c01, c11;
      if (tt == 0 && ss == 0) {
        dmx = m0v; dmy = m1v;
        c00 = sg_t[0];
        c01 = 0.5f * (sg_t[1] + sg_t[4]);
        c11 = sg_t[5];
      } else if (tt == 1 && ss == 1) {
        dmx = m2v; dmy = m3v;
        c00 = sg_t[10];
        c01 = 0.5f * (sg_t[11] + sg_t[14]);
        c11 = sg_t[15];
      } else {
        dmx = 0.5f * (m0v + m2v); dmy = 0.5f * (m1v + m3v);
        float s00 = sg_t[0];
        float s02 = 0.5f * (sg_t[2] + sg_t[8]);
        float s22 = sg_t[10];
        float s01 = 0.5f * (sg_t[1] + sg_t[4]);
        float s03 = 0.5f * (sg_t[3] + sg_t[12]);
        float s21 = 0.5f * (sg_t[9] + sg_t[6]);
        float s23 = 0.5f * (sg_t[11] + sg_t[14]);
        float s11 = sg_t[5];
        float s13 = 0.5f * (sg_t[7] + sg_t[13]);
        float s33 = sg_t[15];
        c00 = 0.25f * (s00 + s02 + s02 + s22);
        c01 = 0.25f * (s01 + s03 + s21 + s23);
        c11 = 0.25f * (s11 + s13 + s13 + s33);
      }
      float D00 = 1.0001f + 2.0f * c00;
      float D01 = 2.0f * c01;
      float D11 = 1.0001f + 2.0f * c11;
      float det = D00 * D11 - D01 * D01;
      float inv = 1.0f / det;
      tsb[tid * 6 + 0] = dmx;
      tsb[tid * 6 + 1] = dmy;
      tsb[tid * 6 + 2] = D11 * inv;
      tsb[tid * 6 + 3] = -D01 * inv;
      tsb[tid * 6 + 4] = D00 * inv;
      tsb[tid * 6 + 5] = __logf(det);
    }
    __syncthreads();

    // ---- build A into Wm, one pass: unit=(row, col-half), 4 lanes/unit ----
    {
      const int unit = tid >> 2, q = tid & 3;
      const int r = unit >> 1, ss = unit & 1, tt = r >> 6, i = r & 63;
      const float* tp = tsb + (tt * 2 + ss) * 6;
      float dmx = tp[0], dmy = tp[1], d00 = tp[2], d01 = tp[3], d11 = tp[4], ldts = tp[5];
      float cix = coords[2 * i], ciy = coords[2 * i + 1];
      float kv[16];
      float rsum = 0.0f;
      const float* cj = coords + q * 32;
      #pragma unroll
      for (int u = 0; u < 16; u++) {
        float dx = cix - cj[2 * u] - dmx;
        float dy = ciy - cj[2 * u + 1] - dmy;
        float qf = d00 * dx * dx + 2.0f * d01 * dx * dy + d11 * dy * dy;
        kv[u] = __expf(-0.5f * (qf + ldts));
        rsum += kv[u];
      }
      float rtot = rsum + __shfl_xor(rsum, 1);
      rtot += __shfl_xor(rtot, 2);
      float cv = (tt == 0) ? ((ss == 0) ? cpl00 : cpl01)
                           : ((ss == 0) ? cpl10 : cpl11);
      float norm = cv / fmaxf(rtot, 1e-6f);
      #pragma unroll
      for (int u = 0; u < 16; u++) kv[u] *= norm;
      const int rl = r & 63;
      if (ss == (r >> 6) && (rl >> 4) == q) kv[rl & 15] += 1.0f - damping;
      float* wrow = Wm + r * LDP + ss * 64 + q * 16;
      #pragma unroll
      for (int u4 = 0; u4 < 4; u4++)
        *(float4*)&wrow[u4 * 4] =
            make_float4(kv[u4 * 4], kv[u4 * 4 + 1], kv[u4 * 4 + 2], kv[u4 * 4 + 3]);
    }
    __syncthreads();

    // ---- m = A m (8-way k-split) ----
    {
      const int r = tid >> 3, q8 = tid & 7;
      const float* arow = Wm + r * LDP + q8 * 16;
      const float* mq = mv + q8 * 16;
      float s = 0.0f;
      #pragma unroll
      for (int k = 0; k < 16; k++) s = fmaf(arow[k], mq[k], s);
      gtmp[r * 8 + q8] = s;
    }
    __syncthreads();
    if (tid < DQ) {
      float s = 0.0f;
      #pragma unroll
      for (int u = 0; u < 8; u++) s += gtmp[8 * tid + u];
      mv[tid] = s;
    }

    // ---- T = A P, written TRANSPOSED into Pm (z-split k-parity) ----
    {
      float acc[4][8];
      #pragma unroll
      for (int i = 0; i < 4; i++)
        #pragma unroll
        for (int j = 0; j < 8; j++) acc[i][j] = 0.0f;
      for (int c = z; c < 32; c += 2) {
        const int k = c * 4;
        float av[4][4];
        #pragma unroll
        for (int i = 0; i < 4; i++) {
          float4 a4 = *(const float4*)&Wm[(r0 + i) * LDP + k];
          av[i][0] = a4.x; av[i][1] = a4.y; av[i][2] = a4.z; av[i][3] = a4.w;
        }
        #pragma unroll
        for (int kk = 0; kk < 4; kk++) {
          float4 pL = *(const float4*)&Pm[(k + kk) * LDP + cL];
          float4 pR = *(const float4*)&Pm[(k + kk) * LDP + cR];
          float pp[8] = {pL.x, pL.y, pL.z, pL.w, pR.x, pR.y, pR.z, pR.w};
          #pragma unroll
          for (int i = 0; i < 4; i++)
            #pragma unroll
            for (int j = 0; j < 8; j++) acc[i][j] = fmaf(av[i][kk], pp[j], acc[i][j]);
        }
      }
      __syncthreads();
      if (z == 0) {
        #pragma unroll
        for (int j = 0; j < 4; j++)
          *(float4*)&Pm[(cL + j) * LDP + r0] =
              make_float4(acc[0][j], acc[1][j], acc[2][j], acc[3][j]);
        #pragma unroll
        for (int j = 0; j < 4; j++)
          *(float4*)&Pm[(cR + j) * LDP + r0] =
              make_float4(acc[0][4 + j], acc[1][4 + j], acc[2][4 + j], acc[3][4 + j]);
      }
      __syncthreads();
      if (z == 1) {
        #pragma unroll
        for (int j = 0; j < 4; j++) {
          float4 v = *(float4*)&Pm[(cL + j) * LDP + r0];
          v.x += acc[0][j]; v.y += acc[1][j]; v.z += acc[2][j]; v.w += acc[3][j];
          *(float4*)&Pm[(cL + j) * LDP + r0] = v;
        }
        #pragma unroll
        for (int j = 0; j < 4; j++) {
          float4 v = *(float4*)&Pm[(cR + j) * LDP + r0];
          v.x += acc[0][4 + j]; v.y += acc[1][4 + j];
          v.z += acc[2][4 + j]; v.w += acc[3][4 + j];
          *(float4*)&Pm[(cR + j) * LDP + r0] = v;
        }
      }
      __syncthreads();

      // ---- P' = A * Tt + q2 I: symmetric output, lower tiles only ----
      #pragma unroll
      for (int i = 0; i < 4; i++)
        #pragma unroll
        for (int j = 0; j < 8; j++) acc[i][j] = 0.0f;
      if (doL) {
        for (int c = z; c < 32; c += 2) {
          const int k = c * 4;
          float av[4][4];
          #pragma unroll
          for (int i = 0; i < 4; i++) {
            float4 a4 = *(const float4*)&Wm[(r0 + i) * LDP + k];
            av[i][0] = a4.x; av[i][1] = a4.y; av[i][2] = a4.z; av[i][3] = a4.w;
          }
          #pragma unroll
          for (int kk = 0; kk < 4; kk++) {
            float4 pL = *(const float4*)&Pm[(k + kk) * LDP + cL];
            float pl[4] = {pL.x, pL.y, pL.z, pL.w};
            #pragma unroll
            for (int i = 0; i < 4; i++)
              #pragma unroll
              for (int j = 0; j < 4; j++) acc[i][j] = fmaf(av[i][kk], pl[j], acc[i][j]);
          }
          if (doR) {
            #pragma unroll
            for (int kk = 0; kk < 4; kk++) {
              float4 pR = *(const float4*)&Pm[(k + kk) * LDP + cR];
              float pr[4] = {pR.x, pR.y, pR.z, pR.w};
              #pragma unroll
              for (int i = 0; i < 4; i++)
                #pragma unroll
                for (int j = 0; j < 4; j++) acc[i][4 + j] = fmaf(av[i][kk], pr[j], acc[i][4 + j]);
            }
          }
        }
      }
      __syncthreads();
      if (z == 0 && doL) {
        #pragma unroll
        for (int i = 0; i < 4; i++) {
          const int rr = r0 + i;
          float4 vL = make_float4(acc[i][0], acc[i][1], acc[i][2], acc[i][3]);
          if (rr >= cL && rr < cL + 4) {
            if (rr == cL)     vL.x += q2;
            if (rr == cL + 1) vL.y += q2;
            if (rr == cL + 2) vL.z += q2;
            if (rr == cL + 3) vL.w += q2;
          }
          *(float4*)&Pm[rr * LDP + cL] = vL;
        }
        if (doR) {
          #pragma unroll
          for (int i = 0; i < 4; i++) {
            const int rr = r0 + i;
            float4 vR = make_float4(acc[i][4], acc[i][5], acc[i][6], acc[i][7]);
            if (rr >= cR && rr < cR + 4) {
              if (rr == cR)     vR.x += q2;
              if (rr == cR + 1) vR.y += q2;
              if (rr == cR + 2) vR.z += q2;
              if (rr == cR + 3) vR.w += q2;
            }
            *(float4*)&Pm[rr * LDP + cR] = vR;
          }
        }
      }
      __syncthreads();
      if (z == 1 && doL) {
        #pragma unroll
        for (int i = 0; i < 4; i++) {
          float4 vL = *(float4*)&Pm[(r0 + i) * LDP + cL];
          vL.x += acc[i][0]; vL.y += acc[i][1]; vL.z += acc[i][2]; vL.w += acc[i][3];
          *(float4*)&Pm[(r0 + i) * LDP + cL] = vL;
        }
        if (doR) {
          #pragma unroll
          for (int i = 0; i < 4; i++) {
            float4 vR = *(float4*)&Pm[(r0 + i) * LDP + cR];
            vR.x += acc[i][4]; vR.y += acc[i][5]; vR.z += acc[i][6]; vR.w += acc[i][7];
            *(float4*)&Pm[(r0 + i) * LDP + cR] = vR;
          }
        }
      }
      __syncthreads();
      // ---- mirror lower->upper AND stage Wm = P' + r2 I ----
      if (tid < 528) {
        int br, bc; tri_index(tid, br, bc);
        const int R = 4 * br, C = 4 * bc;
        float4 v0 = *(const float4*)&Pm[(R + 0) * LDP + C];
        float4 v1 = *(const float4*)&Pm[(R + 1) * LDP + C];
        float4 v2 = *(const float4*)&Pm[(R + 2) * LDP + C];
        float4 v3 = *(const float4*)&Pm[(R + 3) * LDP + C];
        float4 t0 = make_float4(v0.x, v1.x, v2.x, v3.x);
        float4 t1 = make_float4(v0.y, v1.y, v2.y, v3.y);
        float4 t2 = make_float4(v0.z, v1.z, v2.z, v3.z);
        float4 t3 = make_float4(v0.w, v1.w, v2.w, v3.w);
        if (br > bc) {
          *(float4*)&Pm[(C + 0) * LDP + R] = t0;
          *(float4*)&Pm[(C + 1) * LDP + R] = t1;
          *(float4*)&Pm[(C + 2) * LDP + R] = t2;
          *(float4*)&Pm[(C + 3) * LDP + R] = t3;
          *(float4*)&Wm[(R + 0) * LDP + C] = v0;
          *(float4*)&Wm[(R + 1) * LDP + C] = v1;
          *(float4*)&Wm[(R + 2) * LDP + C] = v2;
          *(float4*)&Wm[(R + 3) * LDP + C] = v3;
          *(float4*)&Wm[(C + 0) * LDP + R] = t0;
          *(float4*)&Wm[(C + 1) * LDP + R] = t1;
          *(float4*)&Wm[(C + 2) * LDP + R] = t2;
          *(float4*)&Wm[(C + 3) * LDP + R] = t3;
        } else {
          v0.x += r2; v1.y += r2; v2.z += r2; v3.w += r2;
          *(float4*)&Wm[(R + 0) * LDP + C] = v0;
          *(float4*)&Wm[(R + 1) * LDP + C] = v1;
          *(float4*)&Wm[(R + 2) * LDP + C] = v2;
          *(float4*)&Wm[(R + 3) * LDP + C] = v3;
        }
      }
      __syncthreads();
    }

    kf_update(zt, r2, Pm, Wm, gtmp, mv, vv, yv, xv, mdiag, red, nll, false);
  }

  if (tid == 0) nll_out[b] = nll;
}

extern "C" __global__ void ide_finalize(const float* __restrict__ part,
                                        float* __restrict__ out) {
  if (threadIdx.x == 0) {
    float s = 0.0f;
    for (int i = 0; i < BQ; i++) s += part[i];
    out[0] = s * (1.0f / BQ);
  }
}

extern "C" void kernel_launch(void* const* d_in, const int* in_sizes, int n_in,
                              void* d_out, int out_size, void* d_ws, size_t ws_size,
                              hipStream_t stream) {
  (void)in_sizes; (void)n_in; (void)out_size; (void)ws_size;
  const float* z_seq        = (const float*)d_in[0];
  const float* site_lon     = (const float*)d_in[1];
  const float* site_lat     = (const float*)d_in[2];
  const float* mu_seq       = (const float*)d_in[3];
  const float* sigma_seq    = (const float*)d_in[4];
  const float* log_q        = (const float*)d_in[5];
  const float* log_r        = (const float*)d_in[6];
  const float* log_p0       = (const float*)d_in[7];
  const float* log_damp     = (const float*)d_in[8];
  const float* init_mean    = (const float*)d_in[9];
  const float* coupling_raw = (const float*)d_in[10];
  float* ws = (float*)d_ws;
  float* out = (float*)d_out;

  const size_t smem_bytes = (size_t)SMEM_FLOATS * sizeof(float);
  hipFuncSetAttribute((const void*)ide_kf_kernel,
                      hipFuncAttributeMaxDynamicSharedMemorySize,
                      (int)smem_bytes);

  hipLaunchKernelGGL(ide_kf_kernel, dim3(BQ), dim3(NTH), smem_bytes, stream,
                     z_seq, site_lon, site_lat, mu_seq, sigma_seq,
                     log_q, log_r, log_p0, log_damp, init_mean, coupling_raw,
                     ws);
  hipLaunchKernelGGL(ide_finalize, dim3(1), dim3(64), 0, stream, ws, out);
}

// Round 5
// 16877.602 us; speedup vs baseline: 1.4006x; 1.4006x over previous
//
#include <hip/hip_runtime.h>
#include <math.h>

// IDE state-space Kalman filter, MI355X (gfx950). Round 5:
// - column-split matmuls (4x4/thread, full k): acc+write only, no merge passes
// - Cholesky lookahead: wave0 factors+inverts next diag block WHILE other
//   waves do the trailing update; panel is race-free row-per-thread (1 phase)
// - GEMV folds into matmul phases; nll (quad+logdet) accumulated in private
//   registers, single block-reduce at the end
// - Wm(=Sm) staging fused into P' write; A-build params per-thread (no tsb)

#define SQ 64
#define DQ 128
#define TQ 128
#define BQ 16
#define LDP 132           // padded LDS row stride (floats); rows 16B-aligned
#define NTH 1024
#define LOG2PI 1.8378770664093454f

#define SMEM_FLOATS 36496

__device__ __forceinline__ float block_reduce_sum(float v, float* red) {
  #pragma unroll
  for (int off = 32; off > 0; off >>= 1) v += __shfl_down(v, off);
  const int tid = threadIdx.x;
  if ((tid & 63) == 0) red[tid >> 6] = v;
  __syncthreads();
  v = 0.0f;
  #pragma unroll
  for (int w = 0; w < NTH / 64; w++) v += red[w];
  __syncthreads();
  return v;
}

// 16x16 Cholesky + lower-triangular inverse, register-resident on wave 0.
// Row layout: lane i (<16) holds row i. All cross-lane moves are uniform-index
// broadcasts (compile to readlane, cheap). Writes L to lower of the diag
// block, 1/Ljj to mdiag, strict part of Ldiag^{-1} transposed to the upper.
__device__ __forceinline__ void chol16(float* __restrict__ Wm,
                                       float* __restrict__ mdiag,
                                       int b0, int lane) {
  float a[16];
  if (lane < 16) {
    const float4* rp = (const float4*)(Wm + (b0 + lane) * LDP + b0);
    float4 q0 = rp[0], q1 = rp[1], q2v = rp[2], q3 = rp[3];
    a[0]=q0.x; a[1]=q0.y; a[2]=q0.z; a[3]=q0.w;
    a[4]=q1.x; a[5]=q1.y; a[6]=q1.z; a[7]=q1.w;
    a[8]=q2v.x; a[9]=q2v.y; a[10]=q2v.z; a[11]=q2v.w;
    a[12]=q3.x; a[13]=q3.y; a[14]=q3.z; a[15]=q3.w;
  } else {
    #pragma unroll
    for (int i = 0; i < 16; i++) a[i] = 1.0f;
  }
  float myrinv = 1.0f;
  #pragma unroll
  for (int j = 0; j < 16; j++) {
    float dj = __shfl(a[j], j);
    float rinv = rsqrtf(dj);
    float lij = a[j] * rinv;       // lane j: dj*rsqrt(dj)=Ljj; lane i>j: Lij
    a[j] = lij;
    if (lane == j) myrinv = rinv;
    #pragma unroll
    for (int k = j + 1; k < 16; k++) {
      float lkj = __shfl(lij, k);
      a[k] = fmaf(-lij, lkj, a[k]);
    }
  }
  if (lane < 16) {
    float4* rp = (float4*)(Wm + (b0 + lane) * LDP + b0);
    rp[0] = make_float4(a[0], a[1], a[2], a[3]);
    rp[1] = make_float4(a[4], a[5], a[6], a[7]);
    rp[2] = make_float4(a[8], a[9], a[10], a[11]);
    rp[3] = make_float4(a[12], a[13], a[14], a[15]);
    mdiag[b0 + lane] = myrinv;
  }
  // inverse: lane c computes column c of Ldiag^{-1}
  float x[16];
  #pragma unroll
  for (int i = 0; i < 16; i++) {
    float s = (i == lane) ? 1.0f : 0.0f;
    #pragma unroll
    for (int k = 0; k < 16; k++) {
      if (k < i) {
        float Lik = __shfl(a[k], i);
        s = fmaf(-Lik, x[k], s);
      }
    }
    float ri = __shfl(myrinv, i);
    x[i] = (i < lane) ? 0.0f : s * ri;
  }
  if (lane < 16) {
    #pragma unroll
    for (int i = 0; i < 16; i++)
      if (i > lane) Wm[(b0 + lane) * LDP + (b0 + i)] = x[i];
  }
}

extern "C" __global__ __launch_bounds__(NTH, 4)
void ide_kf_kernel(const float* __restrict__ z_seq,
                   const float* __restrict__ site_lon,
                   const float* __restrict__ site_lat,
                   const float* __restrict__ mu_seq,
                   const float* __restrict__ sigma_seq,
                   const float* __restrict__ log_q,
                   const float* __restrict__ log_r,
                   const float* __restrict__ log_p0,
                   const float* __restrict__ log_damp,
                   const float* __restrict__ init_mean,
                   const float* __restrict__ coupling_raw,
                   float* __restrict__ ws) {
  extern __shared__ float smem[];
  float* Pm     = smem;                  // 128*132
  float* Wm     = Pm + DQ * LDP;         // 128*132
  float* gtmp   = Wm + DQ * LDP;         // 2048
  float* coords = gtmp + 2048;           // 128
  float* mv     = coords + 128;          // 128
  float* vv     = mv + DQ;               // 128
  float* yv     = vv + DQ;               // 128
  float* mdiag  = yv + DQ;               // 128
  float* red    = mdiag + DQ;            // 16

  const int tid = threadIdx.x;
  const int lane = tid & 63;
  const int b = blockIdx.x;
  float* nll_out = ws;

  const float r2 = __expf(2.0f * log_r[0]);
  const float q2 = __expf(2.0f * log_q[0]);
  const float p0sq = __expf(2.0f * log_p0[0]);
  const float damping = __expf(log_damp[0]);
  const float cpl00 = 1.0f + 0.25f * tanhf(coupling_raw[0]);
  const float cpl01 = 0.25f * tanhf(coupling_raw[1]);
  const float cpl10 = 0.25f * tanhf(coupling_raw[2]);
  const float cpl11 = 1.0f + 0.25f * tanhf(coupling_raw[3]);
  const float inv_r2 = 1.0f / r2;

  const int z = tid >> 9, t9 = tid & 511;
  const int cg = t9 & 15, rg = t9 >> 4;
  const int r0 = rg * 4, c0 = z * 64 + cg * 4;

  // ---- lon/lat projection ----
  float myLon = (tid < SQ) ? site_lon[tid] : 0.0f;
  float myLat = (tid < SQ) ? site_lat[tid] : 0.0f;
  float lat0 = block_reduce_sum(myLat, red) * (1.0f / 64.0f);
  float lon0 = block_reduce_sum(myLon, red) * (1.0f / 64.0f);
  if (tid < SQ) {
    const float km = 111.32f;
    float cs = cosf(lat0 * 0.017453292519943295f);
    coords[2 * tid]     = (myLon - lon0) * (km * cs);
    coords[2 * tid + 1] = (myLat - lat0) * km;
  }
  __syncthreads();
  float dsum = 0.0f, dcnt = 0.0f;
  for (int idx = tid; idx < SQ * SQ; idx += NTH) {
    int i = idx >> 6, j = idx & 63;
    float dx = coords[2 * i] - coords[2 * j];
    float dy = coords[2 * i + 1] - coords[2 * j + 1];
    float d = sqrtf(dx * dx + dy * dy + 1e-12f);
    dsum += d;
    if (d > 1e-6f) dcnt += 1.0f;
  }
  dsum = block_reduce_sum(dsum, red);
  dcnt = block_reduce_sum(dcnt, red);
  float scale = dsum / fmaxf(dcnt, 1.0f);
  float sdiv = 1.0f / fmaxf(scale, 1e-6f);
  if (tid < SQ) { coords[2 * tid] *= sdiv; coords[2 * tid + 1] *= sdiv; }

  // ---- init: Pm = p0sq I, Wm = (p0sq+r2) I, mv = init_mean ----
  for (int e = tid; e < (DQ * LDP) / 4; e += NTH) {
    ((float4*)Pm)[e] = make_float4(0.0f, 0.0f, 0.0f, 0.0f);
    ((float4*)Wm)[e] = make_float4(0.0f, 0.0f, 0.0f, 0.0f);
  }
  __syncthreads();
  if (tid < DQ) {
    Pm[tid * LDP + tid] = p0sq;
    Wm[tid * LDP + tid] = p0sq + r2;
    mv[tid] = init_mean[tid];
  }
  __syncthreads();

  float nllp = 0.0f;   // private nll partial (quad + logdet pieces)

  #pragma unroll 1
  for (int t = 0; t < TQ; t++) {
    const float* zt = z_seq + ((size_t)b * TQ + t) * DQ;

    if (t > 0) {
      const float* mu_t = mu_seq + ((size_t)b * (TQ - 1) + (t - 1)) * 4;
      const float* sg_t = sigma_seq + ((size_t)b * (TQ - 1) + (t - 1)) * 16;

      // ---- PHASE A: finish m-update (merge gtmp) + build A into Wm ----
      if (tid < DQ) {
        float s = 0.0f;
        #pragma unroll
        for (int u = 0; u < 8; u++) s += gtmp[8 * tid + u];
        mv[tid] += inv_r2 * s;
      }
      {
        const int unit = tid >> 2, q = tid & 3;
        const int r = unit >> 1, ss = unit & 1, tt = r >> 6, i = r & 63;
        float m0 = mu_t[0], m1 = mu_t[1], m2 = mu_t[2], m3 = mu_t[3];
        float dmx, dmy, c00, c01, c11;
        if (tt == 0 && ss == 0) {
          dmx = m0; dmy = m1;
          c00 = sg_t[0]; c01 = 0.5f * (sg_t[1] + sg_t[4]); c11 = sg_t[5];
        } else if (tt == 1 && ss == 1) {
          dmx = m2; dmy = m3;
          c00 = sg_t[10]; c01 = 0.5f * (sg_t[11] + sg_t[14]); c11 = sg_t[15];
        } else {
          dmx = 0.5f * (m0 + m2); dmy = 0.5f * (m1 + m3);
          float s00 = sg_t[0];
          float s02 = 0.5f * (sg_t[2] + sg_t[8]);
          float s22 = sg_t[10];
          float s01 = 0.5f * (sg_t[1] + sg_t[4]);
          float s03 = 0.5f * (sg_t[3] + sg_t[12]);
          float s21 = 0.5f * (sg_t[9] + sg_t[6]);
          float s23 = 0.5f * (sg_t[11] + sg_t[14]);
          float s11 = sg_t[5];
          float s13 = 0.5f * (sg_t[7] + sg_t[13]);
          float s33 = sg_t[15];
          c00 = 0.25f * (s00 + s02 + s02 + s22);
          c01 = 0.25f * (s01 + s03 + s21 + s23);
          c11 = 0.25f * (s11 + s13 + s13 + s33);
        }
        float D00 = 1.0001f + 2.0f * c00;
        float D01 = 2.0f * c01;
        float D11 = 1.0001f + 2.0f * c11;
        float det = D00 * D11 - D01 * D01;
        float dinv = 1.0f / det;
        float d00 = D11 * dinv, d01 = -D01 * dinv, d11 = D00 * dinv;
        float ldts = __logf(det);
        float cix = coords[2 * i], ciy = coords[2 * i + 1];
        const float* cj = coords + q * 32;
        float kv[16];
        float rsum = 0.0f;
        #pragma unroll
        for (int u = 0; u < 16; u++) {
          float dx = cix - cj[2 * u] - dmx;
          float dy = ciy - cj[2 * u + 1] - dmy;
          float qf = d00 * dx * dx + 2.0f * d01 * dx * dy + d11 * dy * dy;
          kv[u] = __expf(-0.5f * (qf + ldts));
          rsum += kv[u];
        }
        float rtot = rsum + __shfl_xor(rsum, 1);
        rtot += __shfl_xor(rtot, 2);
        float cv = (tt == 0) ? ((ss == 0) ? cpl00 : cpl01)
                             : ((ss == 0) ? cpl10 : cpl11);
        float norm = cv / fmaxf(rtot, 1e-6f);
        #pragma unroll
        for (int u = 0; u < 16; u++) kv[u] *= norm;
        if (ss == tt && ((i >> 4) == q)) kv[i & 15] += 1.0f - damping;
        float* wrow = Wm + r * LDP + ss * 64 + q * 16;
        #pragma unroll
        for (int u4 = 0; u4 < 4; u4++)
          *(float4*)&wrow[u4 * 4] =
              make_float4(kv[u4*4], kv[u4*4+1], kv[u4*4+2], kv[u4*4+3]);
      }
      __syncthreads();

      // ---- PHASE T-acc: acc = A*P (4x4, full k) + m=A*m fold ----
      {
        float acc[4][4];
        #pragma unroll
        for (int i = 0; i < 4; i++)
          #pragma unroll
          for (int j = 0; j < 4; j++) acc[i][j] = 0.0f;
        float newm = 0.0f;
        if (tid < DQ) {
          const float* arow = Wm + tid * LDP;
          float s = 0.0f;
          for (int k = 0; k < DQ; k += 4) {
            float4 a4 = *(const float4*)&arow[k];
            float4 m4 = *(const float4*)&mv[k];
            s = fmaf(a4.x, m4.x, s); s = fmaf(a4.y, m4.y, s);
            s = fmaf(a4.z, m4.z, s); s = fmaf(a4.w, m4.w, s);
          }
          newm = s;
        }
        for (int c = 0; c < 32; c++) {
          const int k = c * 4;
          float4 A0 = *(const float4*)&Wm[(r0 + 0) * LDP + k];
          float4 A1 = *(const float4*)&Wm[(r0 + 1) * LDP + k];
          float4 A2 = *(const float4*)&Wm[(r0 + 2) * LDP + k];
          float4 A3 = *(const float4*)&Wm[(r0 + 3) * LDP + k];
          float av[4][4] = {{A0.x,A0.y,A0.z,A0.w},{A1.x,A1.y,A1.z,A1.w},
                            {A2.x,A2.y,A2.z,A2.w},{A3.x,A3.y,A3.z,A3.w}};
          #pragma unroll
          for (int kk = 0; kk < 4; kk++) {
            float4 p4 = *(const float4*)&Pm[(k + kk) * LDP + c0];
            float pa[4] = {p4.x, p4.y, p4.z, p4.w};
            #pragma unroll
            for (int i = 0; i < 4; i++)
              #pragma unroll
              for (int j = 0; j < 4; j++)
                acc[i][j] = fmaf(av[i][kk], pa[j], acc[i][j]);
          }
        }
        __syncthreads();
        // ---- PHASE T-write: Pm = T^T ----
        if (tid < DQ) mv[tid] = newm;
        #pragma unroll
        for (int j = 0; j < 4; j++)
          *(float4*)&Pm[(c0 + j) * LDP + r0] =
              make_float4(acc[0][j], acc[1][j], acc[2][j], acc[3][j]);
        __syncthreads();
      }

      // ---- PHASE P-acc: acc = A * T^T (= A P A^T, symmetric) ----
      {
        float acc[4][4];
        #pragma unroll
        for (int i = 0; i < 4; i++)
          #pragma unroll
          for (int j = 0; j < 4; j++) acc[i][j] = 0.0f;
        for (int c = 0; c < 32; c++) {
          const int k = c * 4;
          float4 A0 = *(const float4*)&Wm[(r0 + 0) * LDP + k];
          float4 A1 = *(const float4*)&Wm[(r0 + 1) * LDP + k];
          float4 A2 = *(const float4*)&Wm[(r0 + 2) * LDP + k];
          float4 A3 = *(const float4*)&Wm[(r0 + 3) * LDP + k];
          float av[4][4] = {{A0.x,A0.y,A0.z,A0.w},{A1.x,A1.y,A1.z,A1.w},
                            {A2.x,A2.y,A2.z,A2.w},{A3.x,A3.y,A3.z,A3.w}};
          #pragma unroll
          for (int kk = 0; kk < 4; kk++) {
            float4 p4 = *(const float4*)&Pm[(k + kk) * LDP + c0];
            float pa[4] = {p4.x, p4.y, p4.z, p4.w};
            #pragma unroll
            for (int i = 0; i < 4; i++)
              #pragma unroll
              for (int j = 0; j < 4; j++)
                acc[i][j] = fmaf(av[i][kk], pa[j], acc[i][j]);
          }
        }
        __syncthreads();
        // ---- PHASE P-write: Pm = P'+q2 I ; Wm = P'+(q2+r2) I ----
        #pragma unroll
        for (int i = 0; i < 4; i++) {
          const int rr = r0 + i;
          float4 v4 = make_float4(acc[i][0], acc[i][1], acc[i][2], acc[i][3]);
          float4 w4 = v4;
          if (rr >= c0 && rr < c0 + 4) {
            if (rr == c0)     { v4.x += q2; w4.x += q2 + r2; }
            if (rr == c0 + 1) { v4.y += q2; w4.y += q2 + r2; }
            if (rr == c0 + 2) { v4.z += q2; w4.z += q2 + r2; }
            if (rr == c0 + 3) { v4.w += q2; w4.w += q2 + r2; }
          }
          *(float4*)&Pm[rr * LDP + c0] = v4;
          *(float4*)&Wm[rr * LDP + c0] = w4;
        }
        __syncthreads();
      }
    }

    // ================= measurement update =================
    // ---- PHASE K0: wave0 factor+invert diag 0 ; vv compute ----
    if (tid < 64) {
      chol16(Wm, mdiag, 0, lane);
    } else if (tid < 192) {
      const int i = tid - 64;
      vv[i] = zt[i] - mv[i];
    }
    __syncthreads();

    // ---- chol with lookahead ----
    #pragma unroll 1
    for (int kb = 0; kb < 7; kb++) {
      const int b0k = kb * 16, base = b0k + 16, nbelow = DQ - base;
      // PHASE KP: panel rows (row-per-thread, race-free)
      if (tid < nbelow) {
        const int r = base + tid;
        float* wr = Wm + r * LDP + b0k;
        float w[16];
        #pragma unroll
        for (int u4 = 0; u4 < 4; u4++) {
          float4 w4 = *(const float4*)&wr[u4 * 4];
          w[u4*4] = w4.x; w[u4*4+1] = w4.y; w[u4*4+2] = w4.z; w[u4*4+3] = w4.w;
        }
        float out[16];
        #pragma unroll
        for (int j = 0; j < 16; j++) {
          float s = w[j] * mdiag[b0k + j];
          #pragma unroll
          for (int l = 0; l < 16; l++) {
            if (l < j) s = fmaf(w[l], Wm[(b0k + l) * LDP + b0k + j], s);
          }
          out[j] = s;
        }
        #pragma unroll
        for (int u4 = 0; u4 < 4; u4++)
          *(float4*)&wr[u4 * 4] =
              make_float4(out[u4*4], out[u4*4+1], out[u4*4+2], out[u4*4+3]);
      }
      __syncthreads();
      // PHASE KT: wave0 updates+factors+inverts diag kb+1 || trailing rest
      if (tid < 64) {
        #pragma unroll
        for (int u = 0; u < 4; u++) {
          const int o = lane * 4 + u;
          const int mr = o >> 4, mc = o & 15;
          if (mr >= mc) {
            const float* pi = Wm + (base + mr) * LDP + b0k;
            const float* pj = Wm + (base + mc) * LDP + b0k;
            float s = 0.0f;
            #pragma unroll
            for (int c4 = 0; c4 < 4; c4++) {
              float4 xa = *(const float4*)&pi[c4 * 4];
              float4 yb = *(const float4*)&pj[c4 * 4];
              s = fmaf(xa.x, yb.x, s); s = fmaf(xa.y, yb.y, s);
              s = fmaf(xa.z, yb.z, s); s = fmaf(xa.w, yb.w, s);
            }
            Wm[(base + mr) * LDP + base + mc] -= s;
          }
        }
        chol16(Wm, mdiag, base, lane);
      } else if (tid >= 256) {
        const int grp = (tid >> 8) - 1;      // 0..2
        const int t8 = tid & 255;
        const int mrow = t8 >> 4, mcol = t8 & 15;
        const int mb = 7 - kb;
        int cnt = 0;
        for (int bi = 0; bi < mb; bi++) {
          for (int bj = 0; bj <= bi; bj++) {
            if (bi | bj) {
              if (cnt % 3 == grp && (bi > bj || mrow >= mcol)) {
                const int i = base + bi * 16 + mrow;
                const int j = base + bj * 16 + mcol;
                const float* pi = Wm + i * LDP + b0k;
                const float* pj = Wm + j * LDP + b0k;
                float s = 0.0f;
                #pragma unroll
                for (int c4 = 0; c4 < 4; c4++) {
                  float4 xa = *(const float4*)&pi[c4 * 4];
                  float4 yb = *(const float4*)&pj[c4 * 4];
                  s = fmaf(xa.x, yb.x, s); s = fmaf(xa.y, yb.y, s);
                  s = fmaf(xa.z, yb.z, s); s = fmaf(xa.w, yb.w, s);
                }
                Wm[i * LDP + j] -= s;
              }
              cnt++;
            }
          }
        }
      }
      __syncthreads();
    }

    // ---- trinv off-diagonal blocks of M = L^-1 ----
    #pragma unroll 1
    for (int d = 1; d < 8; d++) {
      const int z4 = tid >> 8;
      const int t8 = tid & 255;
      const int i16 = t8 >> 4, j16 = t8 & 15;
      for (int nb = z4; nb + d < 8; nb += 4) {
        const int J = nb, I = nb + d;
        const float* Lrow = Wm + (I * 16 + i16) * LDP + J * 16;
        const float* Mrow = Wm + (J * 16 + j16) * LDP + J * 16;
        const float md = mdiag[J * 16 + j16];
        float g = 0.0f;
        #pragma unroll
        for (int c4 = 0; c4 < 4; c4++) {
          float4 lv = *(const float4*)&Lrow[c4 * 4];
          float4 mq = *(const float4*)&Mrow[c4 * 4];
          float w0 = (c4*4+0 > j16) ? mq.x : ((c4*4+0 == j16) ? md : 0.0f);
          float w1 = (c4*4+1 > j16) ? mq.y : ((c4*4+1 == j16) ? md : 0.0f);
          float w2 = (c4*4+2 > j16) ? mq.z : ((c4*4+2 == j16) ? md : 0.0f);
          float w3 = (c4*4+3 > j16) ? mq.w : ((c4*4+3 == j16) ? md : 0.0f);
          g = fmaf(lv.x, w0, g); g = fmaf(lv.y, w1, g);
          g = fmaf(lv.z, w2, g); g = fmaf(lv.w, w3, g);
        }
        for (int K = J + 1; K < I; K++) {
          const float* LK = Lrow + (K - J) * 16;
          const float* MK = Wm + (J * 16 + j16) * LDP + K * 16;
          #pragma unroll
          for (int c4 = 0; c4 < 4; c4++) {
            float4 lv = *(const float4*)&LK[c4 * 4];
            float4 mq = *(const float4*)&MK[c4 * 4];
            g = fmaf(lv.x, mq.x, g); g = fmaf(lv.y, mq.y, g);
            g = fmaf(lv.z, mq.z, g); g = fmaf(lv.w, mq.w, g);
          }
        }
        gtmp[nb * 256 + t8] = g;
      }
      __syncthreads();
      for (int nb = z4; nb + d < 8; nb += 4) {
        const int J = nb, I = nb + d;
        const float* gb = gtmp + nb * 256;
        float s = mdiag[I * 16 + i16] * gb[i16 * 16 + j16];
        for (int k = 0; k < i16; k++)
          s = fmaf(Wm[(I * 16 + k) * LDP + I * 16 + i16], gb[k * 16 + j16], s);
        Wm[(J * 16 + j16) * LDP + (I * 16 + i16)] = -s;
      }
      __syncthreads();
    }

    // ---- PHASE Y-acc: Y = M*P (triangular k<=row) + y=Mv + logdet fold ----
    {
      float acc[4][4];
      #pragma unroll
      for (int i = 0; i < 4; i++)
        #pragma unroll
        for (int j = 0; j < 4; j++) acc[i][j] = 0.0f;
      if (tid < DQ) {
        nllp -= __logf(mdiag[tid]);          // 0.5*logdet contribution
        float s = mdiag[tid] * vv[tid];
        for (int k = 0; k < tid; k++) s = fmaf(Wm[k * LDP + tid], vv[k], s);
        yv[tid] = s;
      }
      for (int c = 0; c < rg; c++) {
        const int k = c * 4;
        #pragma unroll
        for (int kk = 0; kk < 4; kk++) {
          float4 cv4 = *(const float4*)&Wm[(k + kk) * LDP + r0];
          float4 p4  = *(const float4*)&Pm[(k + kk) * LDP + c0];
          float cva[4] = {cv4.x, cv4.y, cv4.z, cv4.w};
          float pa[4]  = {p4.x, p4.y, p4.z, p4.w};
          #pragma unroll
          for (int i = 0; i < 4; i++)
            #pragma unroll
            for (int j = 0; j < 4; j++)
              acc[i][j] = fmaf(cva[i], pa[j], acc[i][j]);
        }
      }
      #pragma unroll
      for (int kk = 0; kk < 4; kk++) {
        float4 cv4 = *(const float4*)&Wm[(r0 + kk) * LDP + r0];
        float4 p4  = *(const float4*)&Pm[(r0 + kk) * LDP + c0];
        float cva[4] = {cv4.x, cv4.y, cv4.z, cv4.w};
        float pa[4]  = {p4.x, p4.y, p4.z, p4.w};
        #pragma unroll
        for (int i = 0; i < 4; i++) {
          float coef = (kk < i) ? cva[i] : ((kk == i) ? mdiag[r0 + i] : 0.0f);
          #pragma unroll
          for (int j = 0; j < 4; j++)
            acc[i][j] = fmaf(coef, pa[j], acc[i][j]);
        }
      }
      __syncthreads();
      #pragma unroll
      for (int i = 0; i < 4; i++)
        *(float4*)&Pm[(r0 + i) * LDP + c0] =
            make_float4(acc[i][0], acc[i][1], acc[i][2], acc[i][3]);
      __syncthreads();
    }

    // ---- PHASE Pn-acc: Pn = r2*M^T*Y (k>=row) + x=M^T y + quad fold ----
    {
      float acc[4][4];
      #pragma unroll
      for (int i = 0; i < 4; i++)
        #pragma unroll
        for (int j = 0; j < 4; j++) acc[i][j] = 0.0f;
      if (z == 1 && t9 >= 384) {
        const int i = t9 - 384;
        float s = mdiag[i] * yv[i];
        for (int k = i + 1; k < DQ; k++)
          s = fmaf(Wm[i * LDP + k], yv[k], s);
        nllp += 0.5f * vv[i] * s;            // 0.5*quad contribution
      }
      {
        float av[4][4];
        #pragma unroll
        for (int i = 0; i < 4; i++) {
          float4 a4 = *(const float4*)&Wm[(r0 + i) * LDP + r0];
          av[i][0] = a4.x; av[i][1] = a4.y; av[i][2] = a4.z; av[i][3] = a4.w;
        }
        #pragma unroll
        for (int kk = 0; kk < 4; kk++) {
          float4 p4 = *(const float4*)&Pm[(r0 + kk) * LDP + c0];
          float pa[4] = {p4.x, p4.y, p4.z, p4.w};
          #pragma unroll
          for (int i = 0; i < 4; i++) {
            float coef = (kk > i) ? av[i][kk]
                       : ((kk == i) ? mdiag[r0 + i] : 0.0f);
            #pragma unroll
            for (int j = 0; j < 4; j++)
              acc[i][j] = fmaf(coef, pa[j], acc[i][j]);
          }
        }
      }
      for (int c = rg + 1; c < 32; c++) {
        const int k = c * 4;
        float4 A0 = *(const float4*)&Wm[(r0 + 0) * LDP + k];
        float4 A1 = *(const float4*)&Wm[(r0 + 1) * LDP + k];
        float4 A2 = *(const float4*)&Wm[(r0 + 2) * LDP + k];
        float4 A3 = *(const float4*)&Wm[(r0 + 3) * LDP + k];
        float av[4][4] = {{A0.x,A0.y,A0.z,A0.w},{A1.x,A1.y,A1.z,A1.w},
                          {A2.x,A2.y,A2.z,A2.w},{A3.x,A3.y,A3.z,A3.w}};
        #pragma unroll
        for (int kk = 0; kk < 4; kk++) {
          float4 p4 = *(const float4*)&Pm[(k + kk) * LDP + c0];
          float pa[4] = {p4.x, p4.y, p4.z, p4.w};
          #pragma unroll
          for (int i = 0; i < 4; i++)
            #pragma unroll
            for (int j = 0; j < 4; j++)
              acc[i][j] = fmaf(av[i][kk], pa[j], acc[i][j]);
        }
      }
      __syncthreads();
      #pragma unroll
      for (int i = 0; i < 4; i++)
        *(float4*)&Pm[(r0 + i) * LDP + c0] =
            make_float4(r2 * acc[i][0], r2 * acc[i][1],
                        r2 * acc[i][2], r2 * acc[i][3]);
      __syncthreads();
    }

    // ---- PHASE MG: partials of Pn*vv (merged into next A phase) ----
    if (t < TQ - 1) {
      const int r = tid >> 3, q8 = tid & 7;
      const float* prow = Pm + r * LDP + q8 * 16;
      const float* vq = vv + q8 * 16;
      float s = 0.0f;
      #pragma unroll
      for (int u = 0; u < 4; u++) {
        float4 p4 = *(const float4*)&prow[u * 4];
        float4 v4 = *(const float4*)&vq[u * 4];
        s = fmaf(p4.x, v4.x, s); s = fmaf(p4.y, v4.y, s);
        s = fmaf(p4.z, v4.z, s); s = fmaf(p4.w, v4.w, s);
      }
      gtmp[r * 8 + q8] = s;
      __syncthreads();
    }
  }

  float total = block_reduce_sum(nllp, red);
  if (tid == 0)
    nll_out[b] = total + (float)TQ * 0.5f * (float)DQ * LOG2PI;
}

extern "C" __global__ void ide_finalize(const float* __restrict__ part,
                                        float* __restrict__ out) {
  if (threadIdx.x == 0) {
    float s = 0.0f;
    for (int i = 0; i < BQ; i++) s += part[i];
    out[0] = s * (1.0f / BQ);
  }
}

extern "C" void kernel_launch(void* const* d_in, const int* in_sizes, int n_in,
                              void* d_out, int out_size, void* d_ws, size_t ws_size,
                              hipStream_t stream) {
  (void)in_sizes; (void)n_in; (void)out_size; (void)ws_size;
  const float* z_seq        = (const float*)d_in[0];
  const float* site_lon     = (const float*)d_in[1];
  const float* site_lat     = (const float*)d_in[2];
  const float* mu_seq       = (const float*)d_in[3];
  const float* sigma_seq    = (const float*)d_in[4];
  const float* log_q        = (const float*)d_in[5];
  const float* log_r        = (const float*)d_in[6];
  const float* log_p0       = (const float*)d_in[7];
  const float* log_damp     = (const float*)d_in[8];
  const float* init_mean    = (const float*)d_in[9];
  const float* coupling_raw = (const float*)d_in[10];
  float* ws = (float*)d_ws;
  float* out = (float*)d_out;

  const size_t smem_bytes = (size_t)SMEM_FLOATS * sizeof(float);
  hipFuncSetAttribute((const void*)ide_kf_kernel,
                      hipFuncAttributeMaxDynamicSharedMemorySize,
                      (int)smem_bytes);

  hipLaunchKernelGGL(ide_kf_kernel, dim3(BQ), dim3(NTH), smem_bytes, stream,
                     z_seq, site_lon, site_lat, mu_seq, sigma_seq,
                     log_q, log_r, log_p0, log_damp, init_mean, coupling_raw,
                     ws);
  hipLaunchKernelGGL(ide_finalize, dim3(1), dim3(64), 0, stream, ws, out);
}